// Round 6
// baseline (453.912 us; speedup 1.0000x reference)
//
#include <hip/hip_runtime.h>
#include <hip/hip_bf16.h>

// ---------------- problem constants ----------------
#define N_NODES 10000
#define E_REAL  80000
#define E_TOTAL 90000
#define IN_DIM  768
#define HID     512
#define HEADS   4
#define OUT_DIM 768
#define HD1     (HEADS * HID)   // 2048
#define NEG_SLOPE 0.2f
#define H1_HSTRIDE (N_NODES * HID)   // 5,120,000 elements per head slice

typedef unsigned short ushort_t;
typedef unsigned int uint_t;

// ---------------- bf16 helpers ----------------
__device__ inline float b2f(ushort_t u) { return __uint_as_float(((uint_t)u) << 16); }
__device__ inline ushort_t f2b(float f) {
    __hip_bfloat16 h = __float2bfloat16(f);   // RNE
    return *reinterpret_cast<ushort_t*>(&h);
}

__device__ inline void edge_sd(const int* __restrict__ ei, int e, int& s, int& d) {
    if (e < E_REAL) { s = ei[e]; d = ei[E_REAL + e]; }
    else            { s = e - E_REAL; d = s; }   // self-loop
}

// async global->LDS, 16 B per lane; LDS dest = uniform base + lane*16
#define GLDS(g, l) __builtin_amdgcn_global_load_lds( \
    (const __attribute__((address_space(1))) void*)(g), \
    (__attribute__((address_space(3))) void*)(l), 16, 0, 0)

// ---------------- workspace layout (bytes) ----------------
static const long B_H1B  = 0L;           // h1b bf16 (head-major): 40,960,000
static const long B_HB   = 40960000L;    // hb  bf16 (row-major):  40,960,000
static const long B_XB   = 81920000L;    // xb / h2b bf16: 15,360,000
static const long B_W1T  = 97280000L;    // W1^T bf16
static const long B_W2T  = 100425728L;   // W2^T bf16
static const long B_SM   = 103571456L;
// small-buffer offsets (floats/ints, relative to sm)
static const long SM_AS1   = 0;         // 40000
static const long SM_AD1   = 40000;
static const long SM_DEN1  = 120000;
static const long SM_E1    = 160000;    // 360000
static const long SM_AS2   = 520000;
static const long SM_AD2   = 530000;
static const long SM_DEN2  = 550000;
static const long SM_E2    = 560000;    // 90000
static const long SM_CNT   = 650000;    // 10000 ints (zeroed each call)
static const long SM_ROWS  = 660000;    // 10001 ints
static const long SM_CURS  = 670016;    // 10000 ints
static const long SM_END   = 680032;
static const long B_CSRS = B_SM + SM_END * 4;   // 90000 ints (src)
static const long B_CSRE = B_CSRS + 360000L;    // 90000 ints (eid)

// ---------------- cast fp32 -> bf16 (row-major, 8/thread) ----------------
__global__ __launch_bounds__(256)
void cast_bf16(const float* __restrict__ in, ushort_t* __restrict__ o, long n) {
    long i = ((long)blockIdx.x * 256 + threadIdx.x) * 8;
    if (i >= n) return;
    float4 v0 = *(const float4*)(in + i);
    float4 v1 = *(const float4*)(in + i + 4);
    ushort_t r[8] = {f2b(v0.x), f2b(v0.y), f2b(v0.z), f2b(v0.w),
                     f2b(v1.x), f2b(v1.y), f2b(v1.z), f2b(v1.w)};
    *(uint4*)(o + i) = *(uint4*)r;
}

// ---------------- cast + transpose: W[K][N] fp32 -> WT[N][K] bf16 ----------
__global__ __launch_bounds__(256)
void cast_transpose(const float* __restrict__ W, ushort_t* __restrict__ WT,
                    int K, int N) {
    __shared__ ushort_t t[32][33];
    const int n0 = blockIdx.x * 32, k0 = blockIdx.y * 32;
    const int tx = threadIdx.x & 31, ty = threadIdx.x >> 5;
#pragma unroll
    for (int i = 0; i < 4; ++i) {
        int k = ty + i * 8;
        t[k][tx] = f2b(W[(long)(k0 + k) * N + n0 + tx]);
    }
    __syncthreads();
#pragma unroll
    for (int i = 0; i < 4; ++i) {
        int n = ty + i * 8;
        WT[(long)(n0 + n) * K + k0 + tx] = t[tx][n];
    }
}

// ---------------- bf16 MFMA GEMM (128x128x32, async LDS staging) ----------
typedef short bf16x8 __attribute__((ext_vector_type(8)));
typedef float f32x4 __attribute__((ext_vector_type(4)));

#define BM 128
#define BN 128
#define BK 32

template<int CMODE>
__global__ __launch_bounds__(256)
void gemm_bf16(const ushort_t* __restrict__ A, const ushort_t* __restrict__ BT,
               ushort_t* __restrict__ C, int M, int N, int K) {
    __shared__ ushort_t As[BM * BK];
    __shared__ ushort_t Bs[BN * BK];
    const int tid  = threadIdx.x;
    const int wave = tid >> 6, lane = tid & 63;
    const int quad = lane >> 4, l16 = lane & 15;
    const int bm = blockIdx.y * BM, bn = blockIdx.x * BN;
    const int wr = (wave >> 1) * 64, wc = (wave & 1) * 64;

    const int ch0 = wave * 128 + lane;
    const int ch1 = ch0 + 64;
    const int r0 = ch0 >> 2, c0 = (ch0 & 3) ^ ((r0 >> 1) & 3);
    const int r1 = ch1 >> 2, c1 = (ch1 & 3) ^ ((r1 >> 1) & 3);
    const ushort_t* a0 = A + (long)(bm + r0) * K + c0 * 8;
    const ushort_t* a1 = A + (long)(bm + r1) * K + c1 * 8;
    const ushort_t* b0 = BT + (long)(bn + r0) * K + c0 * 8;
    const ushort_t* b1 = BT + (long)(bn + r1) * K + c1 * 8;
    ushort_t* lA0 = As + (wave * 128) * 8;        // HW adds lane*16 B
    ushort_t* lA1 = As + (wave * 128 + 64) * 8;
    ushort_t* lB0 = Bs + (wave * 128) * 8;
    ushort_t* lB1 = Bs + (wave * 128 + 64) * 8;

    const int swz = (l16 >> 1) & 3;
    f32x4 acc[4][4] = {};

    for (int k0 = 0; k0 < K; k0 += BK) {
        GLDS(a0 + k0, lA0);
        GLDS(a1 + k0, lA1);
        GLDS(b0 + k0, lB0);
        GLDS(b1 + k0, lB1);
        __syncthreads();
        bf16x8 af[4], bfr[4];
#pragma unroll
        for (int i = 0; i < 4; ++i) {
            af[i]  = *(const bf16x8*)(As + ((wr + i * 16 + l16) * 4 + (quad ^ swz)) * 8);
            bfr[i] = *(const bf16x8*)(Bs + ((wc + i * 16 + l16) * 4 + (quad ^ swz)) * 8);
        }
#pragma unroll
        for (int i = 0; i < 4; ++i)
#pragma unroll
            for (int j = 0; j < 4; ++j)
                acc[i][j] = __builtin_amdgcn_mfma_f32_16x16x32_bf16(
                    af[i], bfr[j], acc[i][j], 0, 0, 0);
        __syncthreads();
    }

#pragma unroll
    for (int i = 0; i < 4; ++i) {
#pragma unroll
        for (int r = 0; r < 4; ++r) {
            int row = bm + wr + i * 16 + quad * 4 + r;
            if (row >= M) continue;
#pragma unroll
            for (int j = 0; j < 4; ++j) {
                int col = bn + wc + j * 16 + l16;
                if (CMODE == 0) {
                    C[(long)row * N + col] = f2b(acc[i][j][r]);
                } else {
                    C[(long)(col >> 9) * H1_HSTRIDE + (long)row * HID + (col & 511)]
                        = f2b(acc[i][j][r]);
                }
            }
        }
    }
}

// ---------------- attention dots, layer 1 (head-major h1) ----------------
__global__ __launch_bounds__(256)
void attn1(const ushort_t* __restrict__ h, const float* __restrict__ a_s,
           const float* __restrict__ a_d, float* __restrict__ os,
           float* __restrict__ od) {
    const int n = blockIdx.x;
    const int w = threadIdx.x >> 6, lane = threadIdx.x & 63;
    uint4 hv = *(const uint4*)(h + (long)w * H1_HSTRIDE + (long)n * HID + lane * 8);
    const float* asp = a_s + w * HID + lane * 8;
    const float* adp = a_d + w * HID + lane * 8;
    const ushort_t* pb = (const ushort_t*)&hv;
    float ps = 0.f, pd = 0.f;
#pragma unroll
    for (int c = 0; c < 8; ++c) {
        float v = b2f(pb[c]);
        ps += v * asp[c];
        pd += v * adp[c];
    }
#pragma unroll
    for (int off = 32; off > 0; off >>= 1) {
        ps += __shfl_down(ps, off);
        pd += __shfl_down(pd, off);
    }
    if (lane == 0) { os[n * HEADS + w] = ps; od[n * HEADS + w] = pd; }
}

// ---------------- attention dots, layer 2 (H=1, D=768) -------------------
__global__ __launch_bounds__(256)
void attn2(const ushort_t* __restrict__ h, const float* __restrict__ a_s,
           const float* __restrict__ a_d, float* __restrict__ os,
           float* __restrict__ od) {
    __shared__ float rs[4], rd[4];
    const int n = blockIdx.x, tid = threadIdx.x;
    const int w = tid >> 6, lane = tid & 63;
    float ps = 0.f, pd = 0.f;
#pragma unroll
    for (int j = 0; j < 3; ++j) {
        int c = tid + j * 256;
        float v = b2f(h[(long)n * OUT_DIM + c]);
        ps += v * a_s[c];
        pd += v * a_d[c];
    }
#pragma unroll
    for (int off = 32; off > 0; off >>= 1) {
        ps += __shfl_down(ps, off);
        pd += __shfl_down(pd, off);
    }
    if (lane == 0) { rs[w] = ps; rd[w] = pd; }
    __syncthreads();
    if (tid == 0) {
        os[n] = rs[0] + rs[1] + rs[2] + rs[3];
        od[n] = rd[0] + rd[1] + rd[2] + rd[3];
    }
}

// ---------------- fused edge softmax numerator + denom -------------------
__global__ __launch_bounds__(256)
void edge_soft(const int* __restrict__ ei, int H,
               const float* __restrict__ as_n, const float* __restrict__ ad_n,
               float* __restrict__ ebuf, float* __restrict__ denom) {
    int idx = blockIdx.x * 256 + threadIdx.x;
    if (idx >= E_TOTAL * H) return;
    int e = idx / H, hh = idx - e * H;
    int s, d; edge_sd(ei, e, s, d);
    float v = as_n[(long)s * H + hh] + ad_n[(long)d * H + hh];
    v = v > 0.f ? v : NEG_SLOPE * v;
    float ex = expf(v);
    ebuf[idx] = ex;
    atomicAdd(&denom[(long)d * H + hh], ex);
}

// ---------------- CSR build ----------------
__global__ __launch_bounds__(256)
void hist_dst(const int* __restrict__ ei, int* __restrict__ cnt) {
    int e = blockIdx.x * 256 + threadIdx.x;
    if (e >= E_TOTAL) return;
    int s, d; edge_sd(ei, e, s, d);
    atomicAdd(&cnt[d], 1);
}

#define SCAN_CH 40
__global__ __launch_bounds__(256)
void scan_nodes(const int* __restrict__ cnt, int* __restrict__ rows,
                int* __restrict__ curs) {
    __shared__ int part[256];
    const int tid = threadIdx.x;
    const int base = tid * SCAN_CH;
    int local[SCAN_CH];
    int sum = 0;
#pragma unroll
    for (int i = 0; i < SCAN_CH; ++i) {
        int idx = base + i;
        int v = (idx < N_NODES) ? cnt[idx] : 0;
        local[i] = v; sum += v;
    }
    part[tid] = sum;
    __syncthreads();
    for (int off = 1; off < 256; off <<= 1) {
        int v = (tid >= off) ? part[tid - off] : 0;
        __syncthreads();
        part[tid] += v;
        __syncthreads();
    }
    int run = part[tid] - sum;   // exclusive prefix
#pragma unroll
    for (int i = 0; i < SCAN_CH; ++i) {
        int idx = base + i;
        if (idx < N_NODES) { rows[idx] = run; curs[idx] = run; run += local[i]; }
    }
    if (tid == 255) rows[N_NODES] = run;
}

__global__ __launch_bounds__(256)
void scatter_edges(const int* __restrict__ ei, int* __restrict__ curs,
                   int* __restrict__ csr_src, int* __restrict__ csr_eid) {
    int e = blockIdx.x * 256 + threadIdx.x;
    if (e >= E_TOTAL) return;
    int s, d; edge_sd(ei, e, s, d);
    int pos = atomicAdd(&curs[d], 1);
    csr_src[pos] = s;
    csr_eid[pos] = e;
}

// ---------------- layer-1 aggregate: XCD-pinned 128-ch shards ------------
// grid (2500*4, HEADS): sh = bid&3 (fastest dim -> same shard lands on the
// same XCD pair under the bid%8 round-robin heuristic; per-XCD L2 footprint
// = 10000*128*2B = 2.56 MB < 4 MB). Block 256 = 4 waves; wave = node.
// Wave: 4 groups x 16 lanes, group g takes edges k = beg+g, beg+g+4, ...;
// 16 lanes x uint4 = 256 B contiguous per edge; shuffle-reduce across groups.
__global__ __launch_bounds__(256)
void agg1(const int* __restrict__ rows, const int* __restrict__ csr_src,
          const int* __restrict__ csr_eid, const float* __restrict__ ebuf,
          const float* __restrict__ denom, const ushort_t* __restrict__ hf,
          const float* __restrict__ b1, ushort_t* __restrict__ o) {
    const int sh = blockIdx.x & 3, nq = blockIdx.x >> 2;
    const int hh = blockIdx.y;
    const int wave = threadIdx.x >> 6, lane = threadIdx.x & 63;
    const int grp = lane >> 4, l = lane & 15;
    const int n = nq * 4 + wave;              // 2500*4 == N_NODES exactly
    const int beg = rows[n], end = rows[n + 1];
    const ushort_t* hsl = hf + (long)hh * H1_HSTRIDE + sh * 128;
    const float dinv = 1.f / (denom[(long)n * HEADS + hh] + 1e-16f);
    float acc[8] = {};
    for (int k = beg + grp; k < end; k += 4) {
        int s = csr_src[k];
        float al = ebuf[(long)csr_eid[k] * HEADS + hh] * dinv;
        uint4 v = *(const uint4*)(hsl + (long)s * HID + l * 8);
        const ushort_t* p = (const ushort_t*)&v;
#pragma unroll
        for (int c = 0; c < 8; ++c) acc[c] += al * b2f(p[c]);
    }
#pragma unroll
    for (int c = 0; c < 8; ++c) {
        acc[c] += __shfl_down(acc[c], 32);
        acc[c] += __shfl_down(acc[c], 16);
    }
    if (grp == 0) {
        const int ch = hh * HID + sh * 128 + l * 8;   // channel in [0,2048)
        const float* bp = b1 + ch;
        ushort_t r[8];
#pragma unroll
        for (int c = 0; c < 8; ++c) {
            float vv = acc[c] + bp[c];
            r[c] = f2b(vv > 0.f ? vv : expm1f(vv));
        }
        *(uint4*)(o + (long)n * HD1 + ch) = *(uint4*)r;
    }
}

// ---------------- layer-2 aggregate: XCD-pinned 96-ch shards -------------
// grid 2500*8: sh = bid&7 -> per-XCD footprint 10000*96*2B = 1.92 MB.
// Block 256 = 4 waves; wave = node; 4 groups x 16 lanes (12 active).
__global__ __launch_bounds__(256)
void agg2(const int* __restrict__ rows, const int* __restrict__ csr_src,
          const int* __restrict__ csr_eid, const float* __restrict__ ebuf,
          const float* __restrict__ denom, const ushort_t* __restrict__ hf,
          const float* __restrict__ b2, float* __restrict__ out) {
    const int sh = blockIdx.x & 7, nq = blockIdx.x >> 3;
    const int wave = threadIdx.x >> 6, lane = threadIdx.x & 63;
    const int grp = lane >> 4, l = lane & 15;
    const int lc = l < 12 ? l : 0;            // lanes 12..15 duplicate lane 0
    const int n = nq * 4 + wave;
    const int beg = rows[n], end = rows[n + 1];
    const ushort_t* hsl = hf + sh * 96;
    const float dinv = 1.f / (denom[n] + 1e-16f);
    float acc[8] = {};
    for (int k = beg + grp; k < end; k += 4) {
        int s = csr_src[k];
        float al = ebuf[csr_eid[k]] * dinv;
        uint4 v = *(const uint4*)(hsl + (long)s * OUT_DIM + lc * 8);
        const ushort_t* p = (const ushort_t*)&v;
#pragma unroll
        for (int c = 0; c < 8; ++c) acc[c] += al * b2f(p[c]);
    }
#pragma unroll
    for (int c = 0; c < 8; ++c) {
        acc[c] += __shfl_down(acc[c], 32);
        acc[c] += __shfl_down(acc[c], 16);
    }
    if (grp == 0 && l < 12) {
        const int ch = sh * 96 + l * 8;       // channel in [0,768)
        float* op = out + (long)n * OUT_DIM + ch;
        const float* bp = b2 + ch;
#pragma unroll
        for (int c = 0; c < 8; ++c) op[c] = acc[c] + bp[c];
    }
}

extern "C" void kernel_launch(void* const* d_in, const int* in_sizes, int n_in,
                              void* d_out, int out_size, void* d_ws, size_t ws_size,
                              hipStream_t stream) {
    const float* x   = (const float*)d_in[0];
    const int*   ei  = (const int*)d_in[1];
    const float* W1  = (const float*)d_in[2];
    const float* a1s = (const float*)d_in[3];
    const float* a1d = (const float*)d_in[4];
    const float* b1  = (const float*)d_in[5];
    const float* W2  = (const float*)d_in[6];
    const float* a2s = (const float*)d_in[7];
    const float* a2d = (const float*)d_in[8];
    const float* b2  = (const float*)d_in[9];
    float* out = (float*)d_out;
    char* base = (char*)d_ws;

    ushort_t* h1b = (ushort_t*)(base + B_H1B);   // head-major [4][10000][512]
    ushort_t* hb  = (ushort_t*)(base + B_HB);    // row-major  [10000][2048]
    ushort_t* xb  = (ushort_t*)(base + B_XB);
    ushort_t* h2b = xb;
    ushort_t* w1t = (ushort_t*)(base + B_W1T);
    ushort_t* w2t = (ushort_t*)(base + B_W2T);
    float*    sm  = (float*)(base + B_SM);

    float* as1  = sm + SM_AS1;
    float* ad1  = sm + SM_AD1;
    float* den1 = sm + SM_DEN1;
    float* e1   = sm + SM_E1;
    float* as2  = sm + SM_AS2;
    float* ad2  = sm + SM_AD2;
    float* den2 = sm + SM_DEN2;
    float* e2   = sm + SM_E2;
    int* cnt    = (int*)(sm + SM_CNT);
    int* rows   = (int*)(sm + SM_ROWS);
    int* curs   = (int*)(sm + SM_CURS);
    int* csr_src = (int*)(base + B_CSRS);
    int* csr_eid = (int*)(base + B_CSRE);

    // zero den1/den2/cnt (covered by [sm, sm+SM_CNT+10000))
    hipMemsetAsync(sm, 0, (size_t)(SM_CNT + 10000) * sizeof(float), stream);

    // ---------------- casts + CSR build ----------------
    {
        long nx = (long)N_NODES * IN_DIM;
        cast_bf16<<<(int)(nx / 8 / 256 + 1), 256, 0, stream>>>(x, xb, nx);
        cast_transpose<<<dim3(HD1 / 32, IN_DIM / 32), 256, 0, stream>>>(W1, w1t, IN_DIM, HD1);
        cast_transpose<<<dim3(OUT_DIM / 32, HD1 / 32), 256, 0, stream>>>(W2, w2t, HD1, OUT_DIM);
        hist_dst<<<(E_TOTAL + 255) / 256, 256, 0, stream>>>(ei, cnt);
        scan_nodes<<<1, 256, 0, stream>>>(cnt, rows, curs);
        scatter_edges<<<(E_TOTAL + 255) / 256, 256, 0, stream>>>(ei, curs, csr_src, csr_eid);
    }

    // ---------------- layer 1: GATConv(768 -> 512, heads=4, concat) --------
    gemm_bf16<1><<<dim3(HD1 / BN, (N_NODES + BM - 1) / BM), 256, 0, stream>>>(
        xb, w1t, h1b, N_NODES, HD1, IN_DIM);
    attn1<<<N_NODES, 256, 0, stream>>>(h1b, a1s, a1d, as1, ad1);
    {
        int total = E_TOTAL * HEADS;
        edge_soft<<<(total + 255) / 256, 256, 0, stream>>>(ei, HEADS, as1, ad1, e1, den1);
    }
    agg1<<<dim3((N_NODES / 4) * 4, HEADS), 256, 0, stream>>>(
        rows, csr_src, csr_eid, e1, den1, h1b, b1, hb);

    // ---------------- layer 2: GATConv(2048 -> 768, heads=1, mean) ---------
    gemm_bf16<0><<<dim3(OUT_DIM / BN, (N_NODES + BM - 1) / BM), 256, 0, stream>>>(
        hb, w2t, h2b, N_NODES, OUT_DIM, HD1);
    attn2<<<N_NODES, 256, 0, stream>>>(h2b, a2s, a2d, as2, ad2);
    {
        int total = E_TOTAL;
        edge_soft<<<(total + 255) / 256, 256, 0, stream>>>(ei, 1, as2, ad2, e2, den2);
    }
    agg2<<<(N_NODES / 4) * 8, 256, 0, stream>>>(
        rows, csr_src, csr_eid, e2, den2, h2b, b2, out);
}

// Round 7
// 383.056 us; speedup vs baseline: 1.1850x; 1.1850x over previous
//
#include <hip/hip_runtime.h>
#include <hip/hip_bf16.h>

// ---------------- problem constants ----------------
#define N_NODES 10000
#define E_REAL  80000
#define E_TOTAL 90000
#define IN_DIM  768
#define HID     512
#define HEADS   4
#define OUT_DIM 768
#define HD1     (HEADS * HID)   // 2048
#define NEG_SLOPE 0.2f
#define H1_HSTRIDE (N_NODES * HID)   // 5,120,000 elements per head slice

typedef unsigned short ushort_t;
typedef unsigned int uint_t;

// ---------------- bf16 helpers ----------------
__device__ inline float b2f(ushort_t u) { return __uint_as_float(((uint_t)u) << 16); }
__device__ inline ushort_t f2b(float f) {
    __hip_bfloat16 h = __float2bfloat16(f);   // RNE
    return *reinterpret_cast<ushort_t*>(&h);
}

__device__ inline void edge_sd(const int* __restrict__ ei, int e, int& s, int& d) {
    if (e < E_REAL) { s = ei[e]; d = ei[E_REAL + e]; }
    else            { s = e - E_REAL; d = s; }   // self-loop
}

// async global->LDS, 16 B per lane; LDS dest = uniform base + lane*16
#define GLDS(g, l) __builtin_amdgcn_global_load_lds( \
    (const __attribute__((address_space(1))) void*)(g), \
    (__attribute__((address_space(3))) void*)(l), 16, 0, 0)

// ---------------- workspace layout (bytes) ----------------
static const long B_H1B  = 0L;           // h1b bf16 (head-major): 40,960,000
static const long B_HB   = 40960000L;    // hb  bf16 (row-major):  40,960,000
static const long B_XB   = 81920000L;    // xb / h2b bf16: 15,360,000
static const long B_W1T  = 97280000L;    // W1^T bf16
static const long B_W2T  = 100425728L;   // W2^T bf16
static const long B_SM   = 103571456L;
// small-buffer offsets (floats/ints, relative to sm)
static const long SM_AS1   = 0;         // 40000
static const long SM_AD1   = 40000;
static const long SM_DEN1  = 120000;
static const long SM_E1    = 160000;    // 360000
static const long SM_AS2   = 520000;
static const long SM_AD2   = 530000;
static const long SM_DEN2  = 550000;
static const long SM_E2    = 560000;    // 90000
static const long SM_CNT   = 650000;    // 10000 ints (zeroed each call)
static const long SM_ROWS  = 660000;    // 10001 ints
static const long SM_CURS  = 670016;    // 10000 ints
static const long SM_END   = 680032;
static const long B_CSRS = B_SM + SM_END * 4;   // 90000 ints (src)
static const long B_CSRE = B_CSRS + 360000L;    // 90000 ints (eid)

// ---------------- cast fp32 -> bf16 (row-major, 8/thread) ----------------
__global__ __launch_bounds__(256)
void cast_bf16(const float* __restrict__ in, ushort_t* __restrict__ o, long n) {
    long i = ((long)blockIdx.x * 256 + threadIdx.x) * 8;
    if (i >= n) return;
    float4 v0 = *(const float4*)(in + i);
    float4 v1 = *(const float4*)(in + i + 4);
    ushort_t r[8] = {f2b(v0.x), f2b(v0.y), f2b(v0.z), f2b(v0.w),
                     f2b(v1.x), f2b(v1.y), f2b(v1.z), f2b(v1.w)};
    *(uint4*)(o + i) = *(uint4*)r;
}

// ---------------- cast + transpose: W[K][N] fp32 -> WT[N][K] bf16 ----------
__global__ __launch_bounds__(256)
void cast_transpose(const float* __restrict__ W, ushort_t* __restrict__ WT,
                    int K, int N) {
    __shared__ ushort_t t[32][33];
    const int n0 = blockIdx.x * 32, k0 = blockIdx.y * 32;
    const int tx = threadIdx.x & 31, ty = threadIdx.x >> 5;
#pragma unroll
    for (int i = 0; i < 4; ++i) {
        int k = ty + i * 8;
        t[k][tx] = f2b(W[(long)(k0 + k) * N + n0 + tx]);
    }
    __syncthreads();
#pragma unroll
    for (int i = 0; i < 4; ++i) {
        int n = ty + i * 8;
        WT[(long)(n0 + n) * K + k0 + tx] = t[tx][n];
    }
}

// ---------------- bf16 MFMA GEMM (128x128x32, async LDS staging) ----------
typedef short bf16x8 __attribute__((ext_vector_type(8)));
typedef float f32x4 __attribute__((ext_vector_type(4)));

#define BM 128
#define BN 128
#define BK 32

template<int CMODE>
__global__ __launch_bounds__(256)
void gemm_bf16(const ushort_t* __restrict__ A, const ushort_t* __restrict__ BT,
               ushort_t* __restrict__ C, int M, int N, int K) {
    __shared__ ushort_t As[BM * BK];
    __shared__ ushort_t Bs[BN * BK];
    const int tid  = threadIdx.x;
    const int wave = tid >> 6, lane = tid & 63;
    const int quad = lane >> 4, l16 = lane & 15;
    const int bm = blockIdx.y * BM, bn = blockIdx.x * BN;
    const int wr = (wave >> 1) * 64, wc = (wave & 1) * 64;

    const int ch0 = wave * 128 + lane;
    const int ch1 = ch0 + 64;
    const int r0 = ch0 >> 2, c0 = (ch0 & 3) ^ ((r0 >> 1) & 3);
    const int r1 = ch1 >> 2, c1 = (ch1 & 3) ^ ((r1 >> 1) & 3);
    const ushort_t* a0 = A + (long)(bm + r0) * K + c0 * 8;
    const ushort_t* a1 = A + (long)(bm + r1) * K + c1 * 8;
    const ushort_t* b0 = BT + (long)(bn + r0) * K + c0 * 8;
    const ushort_t* b1 = BT + (long)(bn + r1) * K + c1 * 8;
    ushort_t* lA0 = As + (wave * 128) * 8;        // HW adds lane*16 B
    ushort_t* lA1 = As + (wave * 128 + 64) * 8;
    ushort_t* lB0 = Bs + (wave * 128) * 8;
    ushort_t* lB1 = Bs + (wave * 128 + 64) * 8;

    const int swz = (l16 >> 1) & 3;
    f32x4 acc[4][4] = {};

    for (int k0 = 0; k0 < K; k0 += BK) {
        GLDS(a0 + k0, lA0);
        GLDS(a1 + k0, lA1);
        GLDS(b0 + k0, lB0);
        GLDS(b1 + k0, lB1);
        __syncthreads();
        bf16x8 af[4], bfr[4];
#pragma unroll
        for (int i = 0; i < 4; ++i) {
            af[i]  = *(const bf16x8*)(As + ((wr + i * 16 + l16) * 4 + (quad ^ swz)) * 8);
            bfr[i] = *(const bf16x8*)(Bs + ((wc + i * 16 + l16) * 4 + (quad ^ swz)) * 8);
        }
#pragma unroll
        for (int i = 0; i < 4; ++i)
#pragma unroll
            for (int j = 0; j < 4; ++j)
                acc[i][j] = __builtin_amdgcn_mfma_f32_16x16x32_bf16(
                    af[i], bfr[j], acc[i][j], 0, 0, 0);
        __syncthreads();
    }

#pragma unroll
    for (int i = 0; i < 4; ++i) {
#pragma unroll
        for (int r = 0; r < 4; ++r) {
            int row = bm + wr + i * 16 + quad * 4 + r;
            if (row >= M) continue;
#pragma unroll
            for (int j = 0; j < 4; ++j) {
                int col = bn + wc + j * 16 + l16;
                if (CMODE == 0) {
                    C[(long)row * N + col] = f2b(acc[i][j][r]);
                } else {
                    C[(long)(col >> 9) * H1_HSTRIDE + (long)row * HID + (col & 511)]
                        = f2b(acc[i][j][r]);
                }
            }
        }
    }
}

// ---------------- attention dots, layer 1 (head-major h1) ----------------
__global__ __launch_bounds__(256)
void attn1(const ushort_t* __restrict__ h, const float* __restrict__ a_s,
           const float* __restrict__ a_d, float* __restrict__ os,
           float* __restrict__ od) {
    const int n = blockIdx.x;
    const int w = threadIdx.x >> 6, lane = threadIdx.x & 63;
    uint4 hv = *(const uint4*)(h + (long)w * H1_HSTRIDE + (long)n * HID + lane * 8);
    const float* asp = a_s + w * HID + lane * 8;
    const float* adp = a_d + w * HID + lane * 8;
    const ushort_t* pb = (const ushort_t*)&hv;
    float ps = 0.f, pd = 0.f;
#pragma unroll
    for (int c = 0; c < 8; ++c) {
        float v = b2f(pb[c]);
        ps += v * asp[c];
        pd += v * adp[c];
    }
#pragma unroll
    for (int off = 32; off > 0; off >>= 1) {
        ps += __shfl_down(ps, off);
        pd += __shfl_down(pd, off);
    }
    if (lane == 0) { os[n * HEADS + w] = ps; od[n * HEADS + w] = pd; }
}

// ---------------- attention dots, layer 2 (H=1, D=768) -------------------
__global__ __launch_bounds__(256)
void attn2(const ushort_t* __restrict__ h, const float* __restrict__ a_s,
           const float* __restrict__ a_d, float* __restrict__ os,
           float* __restrict__ od) {
    __shared__ float rs[4], rd[4];
    const int n = blockIdx.x, tid = threadIdx.x;
    const int w = tid >> 6, lane = tid & 63;
    float ps = 0.f, pd = 0.f;
#pragma unroll
    for (int j = 0; j < 3; ++j) {
        int c = tid + j * 256;
        float v = b2f(h[(long)n * OUT_DIM + c]);
        ps += v * a_s[c];
        pd += v * a_d[c];
    }
#pragma unroll
    for (int off = 32; off > 0; off >>= 1) {
        ps += __shfl_down(ps, off);
        pd += __shfl_down(pd, off);
    }
    if (lane == 0) { rs[w] = ps; rd[w] = pd; }
    __syncthreads();
    if (tid == 0) {
        os[n] = rs[0] + rs[1] + rs[2] + rs[3];
        od[n] = rd[0] + rd[1] + rd[2] + rd[3];
    }
}

// ---------------- fused edge softmax numerator + denom -------------------
__global__ __launch_bounds__(256)
void edge_soft(const int* __restrict__ ei, int H,
               const float* __restrict__ as_n, const float* __restrict__ ad_n,
               float* __restrict__ ebuf, float* __restrict__ denom) {
    int idx = blockIdx.x * 256 + threadIdx.x;
    if (idx >= E_TOTAL * H) return;
    int e = idx / H, hh = idx - e * H;
    int s, d; edge_sd(ei, e, s, d);
    float v = as_n[(long)s * H + hh] + ad_n[(long)d * H + hh];
    v = v > 0.f ? v : NEG_SLOPE * v;
    float ex = expf(v);
    ebuf[idx] = ex;
    atomicAdd(&denom[(long)d * H + hh], ex);
}

// ---------------- CSR build ----------------
__global__ __launch_bounds__(256)
void hist_dst(const int* __restrict__ ei, int* __restrict__ cnt) {
    int e = blockIdx.x * 256 + threadIdx.x;
    if (e >= E_TOTAL) return;
    int s, d; edge_sd(ei, e, s, d);
    atomicAdd(&cnt[d], 1);
}

#define SCAN_CH 40
__global__ __launch_bounds__(256)
void scan_nodes(const int* __restrict__ cnt, int* __restrict__ rows,
                int* __restrict__ curs) {
    __shared__ int part[256];
    const int tid = threadIdx.x;
    const int base = tid * SCAN_CH;
    int local[SCAN_CH];
    int sum = 0;
#pragma unroll
    for (int i = 0; i < SCAN_CH; ++i) {
        int idx = base + i;
        int v = (idx < N_NODES) ? cnt[idx] : 0;
        local[i] = v; sum += v;
    }
    part[tid] = sum;
    __syncthreads();
    for (int off = 1; off < 256; off <<= 1) {
        int v = (tid >= off) ? part[tid - off] : 0;
        __syncthreads();
        part[tid] += v;
        __syncthreads();
    }
    int run = part[tid] - sum;   // exclusive prefix
#pragma unroll
    for (int i = 0; i < SCAN_CH; ++i) {
        int idx = base + i;
        if (idx < N_NODES) { rows[idx] = run; curs[idx] = run; run += local[i]; }
    }
    if (tid == 255) rows[N_NODES] = run;
}

__global__ __launch_bounds__(256)
void scatter_edges(const int* __restrict__ ei, int* __restrict__ curs,
                   int* __restrict__ csr_src, int* __restrict__ csr_eid) {
    int e = blockIdx.x * 256 + threadIdx.x;
    if (e >= E_TOTAL) return;
    int s, d; edge_sd(ei, e, s, d);
    int pos = atomicAdd(&curs[d], 1);
    csr_src[pos] = s;
    csr_eid[pos] = e;
}

// ---------------- layer-1 aggregate: XCD-pinned shards, 16 nodes/block ---
// grid (4 shards x 625 chunks, HEADS); shard = bid&3 is the fastest dim ->
// per-XCD L2 footprint = 10000*128ch*2B = 2.56 MB (r6 measured FETCH drop).
// Block 256 = 16 node-groups x 16 lanes; each group = one node, iterates its
// edges with 4-deep unroll (r5 shape: batched csr/ebuf loads, 16 feature
// loads in flight per wave, one epilogue per node).
__global__ __launch_bounds__(256)
void agg1(const int* __restrict__ rows, const int* __restrict__ csr_src,
          const int* __restrict__ csr_eid, const float* __restrict__ ebuf,
          const float* __restrict__ denom, const ushort_t* __restrict__ hf,
          const float* __restrict__ b1, ushort_t* __restrict__ o) {
    const int sh = blockIdx.x & 3, chunk = blockIdx.x >> 2;
    const int hh = blockIdx.y;
    const int grp = threadIdx.x >> 4, l = threadIdx.x & 15;
    const int n = chunk * 16 + grp;           // 625*16 == N_NODES exactly
    const int beg = rows[n], end = rows[n + 1];
    const ushort_t* hsl = hf + (long)hh * H1_HSTRIDE + sh * 128;
    const float dinv = 1.f / (denom[(long)n * HEADS + hh] + 1e-16f);
    float acc[8] = {};
    for (int k = beg; k < end; k += 4) {
        int nk = end - k; if (nk > 4) nk = 4;
        uint4 v[4]; float al[4];
#pragma unroll
        for (int u = 0; u < 4; ++u) {
            if (u < nk) {
                int s = csr_src[k + u];
                al[u] = ebuf[(long)csr_eid[k + u] * HEADS + hh] * dinv;
                v[u]  = *(const uint4*)(hsl + (long)s * HID + l * 8);
            }
        }
#pragma unroll
        for (int u = 0; u < 4; ++u) {
            if (u < nk) {
                const ushort_t* p = (const ushort_t*)&v[u];
#pragma unroll
                for (int c = 0; c < 8; ++c) acc[c] += al[u] * b2f(p[c]);
            }
        }
    }
    const int ch = hh * HID + sh * 128 + l * 8;   // channel in [0,2048)
    const float* bp = b1 + ch;
    ushort_t r[8];
#pragma unroll
    for (int c = 0; c < 8; ++c) {
        float vv = acc[c] + bp[c];
        r[c] = f2b(vv > 0.f ? vv : expm1f(vv));
    }
    *(uint4*)(o + (long)n * HD1 + ch) = *(uint4*)r;
}

// ---------------- layer-2 CSR aggregate + bias -> fp32 out (r5 version) --
// 64 threads/node; lane covers 8 ch (uint4) + 4 ch (uint2) = 12 ch.
__global__ __launch_bounds__(64)
void agg2(const int* __restrict__ rows, const int* __restrict__ csr_src,
          const int* __restrict__ csr_eid, const float* __restrict__ ebuf,
          const float* __restrict__ denom, const ushort_t* __restrict__ hf,
          const float* __restrict__ b2, float* __restrict__ out) {
    const int n = blockIdx.x, lane = threadIdx.x;
    const int beg = rows[n], end = rows[n + 1];
    const float dinv = 1.f / (denom[n] + 1e-16f);
    float acc[12] = {};
    for (int k = beg; k < end; k += 4) {
        int nk = end - k; if (nk > 4) nk = 4;
        uint4 v4[4]; uint2 v2[4]; float al[4];
#pragma unroll
        for (int u = 0; u < 4; ++u) {
            if (u < nk) {
                int s = csr_src[k + u];
                al[u] = ebuf[csr_eid[k + u]] * dinv;
                const ushort_t* hp = hf + (long)s * OUT_DIM;
                v4[u] = *(const uint4*)(hp + lane * 8);
                v2[u] = *(const uint2*)(hp + 512 + lane * 4);
            }
        }
#pragma unroll
        for (int u = 0; u < 4; ++u) {
            if (u < nk) {
                const ushort_t* p4 = (const ushort_t*)&v4[u];
                const ushort_t* p2 = (const ushort_t*)&v2[u];
#pragma unroll
                for (int c = 0; c < 8; ++c) acc[c] += al[u] * b2f(p4[c]);
#pragma unroll
                for (int c = 0; c < 4; ++c) acc[8 + c] += al[u] * b2f(p2[c]);
            }
        }
    }
    float* op = out + (long)n * OUT_DIM;
#pragma unroll
    for (int c = 0; c < 8; ++c) op[lane * 8 + c] = acc[c] + b2[lane * 8 + c];
#pragma unroll
    for (int c = 0; c < 4; ++c)
        op[512 + lane * 4 + c] = acc[8 + c] + b2[512 + lane * 4 + c];
}

extern "C" void kernel_launch(void* const* d_in, const int* in_sizes, int n_in,
                              void* d_out, int out_size, void* d_ws, size_t ws_size,
                              hipStream_t stream) {
    const float* x   = (const float*)d_in[0];
    const int*   ei  = (const int*)d_in[1];
    const float* W1  = (const float*)d_in[2];
    const float* a1s = (const float*)d_in[3];
    const float* a1d = (const float*)d_in[4];
    const float* b1  = (const float*)d_in[5];
    const float* W2  = (const float*)d_in[6];
    const float* a2s = (const float*)d_in[7];
    const float* a2d = (const float*)d_in[8];
    const float* b2  = (const float*)d_in[9];
    float* out = (float*)d_out;
    char* base = (char*)d_ws;

    ushort_t* h1b = (ushort_t*)(base + B_H1B);   // head-major [4][10000][512]
    ushort_t* hb  = (ushort_t*)(base + B_HB);    // row-major  [10000][2048]
    ushort_t* xb  = (ushort_t*)(base + B_XB);
    ushort_t* h2b = xb;
    ushort_t* w1t = (ushort_t*)(base + B_W1T);
    ushort_t* w2t = (ushort_t*)(base + B_W2T);
    float*    sm  = (float*)(base + B_SM);

    float* as1  = sm + SM_AS1;
    float* ad1  = sm + SM_AD1;
    float* den1 = sm + SM_DEN1;
    float* e1   = sm + SM_E1;
    float* as2  = sm + SM_AS2;
    float* ad2  = sm + SM_AD2;
    float* den2 = sm + SM_DEN2;
    float* e2   = sm + SM_E2;
    int* cnt    = (int*)(sm + SM_CNT);
    int* rows   = (int*)(sm + SM_ROWS);
    int* curs   = (int*)(sm + SM_CURS);
    int* csr_src = (int*)(base + B_CSRS);
    int* csr_eid = (int*)(base + B_CSRE);

    // zero den1/den2/cnt (covered by [sm, sm+SM_CNT+10000))
    hipMemsetAsync(sm, 0, (size_t)(SM_CNT + 10000) * sizeof(float), stream);

    // ---------------- casts + CSR build ----------------
    {
        long nx = (long)N_NODES * IN_DIM;
        cast_bf16<<<(int)(nx / 8 / 256 + 1), 256, 0, stream>>>(x, xb, nx);
        cast_transpose<<<dim3(HD1 / 32, IN_DIM / 32), 256, 0, stream>>>(W1, w1t, IN_DIM, HD1);
        cast_transpose<<<dim3(OUT_DIM / 32, HD1 / 32), 256, 0, stream>>>(W2, w2t, HD1, OUT_DIM);
        hist_dst<<<(E_TOTAL + 255) / 256, 256, 0, stream>>>(ei, cnt);
        scan_nodes<<<1, 256, 0, stream>>>(cnt, rows, curs);
        scatter_edges<<<(E_TOTAL + 255) / 256, 256, 0, stream>>>(ei, curs, csr_src, csr_eid);
    }

    // ---------------- layer 1: GATConv(768 -> 512, heads=4, concat) --------
    gemm_bf16<1><<<dim3(HD1 / BN, (N_NODES + BM - 1) / BM), 256, 0, stream>>>(
        xb, w1t, h1b, N_NODES, HD1, IN_DIM);
    attn1<<<N_NODES, 256, 0, stream>>>(h1b, a1s, a1d, as1, ad1);
    {
        int total = E_TOTAL * HEADS;
        edge_soft<<<(total + 255) / 256, 256, 0, stream>>>(ei, HEADS, as1, ad1, e1, den1);
    }
    agg1<<<dim3(4 * 625, HEADS), 256, 0, stream>>>(
        rows, csr_src, csr_eid, e1, den1, h1b, b1, hb);

    // ---------------- layer 2: GATConv(2048 -> 768, heads=1, mean) ---------
    gemm_bf16<0><<<dim3(OUT_DIM / BN, (N_NODES + BM - 1) / BM), 256, 0, stream>>>(
        hb, w2t, h2b, N_NODES, OUT_DIM, HD1);
    attn2<<<N_NODES, 256, 0, stream>>>(h2b, a2s, a2d, as2, ad2);
    {
        int total = E_TOTAL;
        edge_soft<<<(total + 255) / 256, 256, 0, stream>>>(ei, 1, as2, ad2, e2, den2);
    }
    agg2<<<N_NODES, 64, 0, stream>>>(
        rows, csr_src, csr_eid, e2, den2, h2b, b2, out);
}

// Round 8
// 343.758 us; speedup vs baseline: 1.3204x; 1.1143x over previous
//
#include <hip/hip_runtime.h>
#include <hip/hip_bf16.h>

// ---------------- problem constants ----------------
#define N_NODES 10000
#define E_REAL  80000
#define E_TOTAL 90000
#define IN_DIM  768
#define HID     512
#define HEADS   4
#define OUT_DIM 768
#define HD1     (HEADS * HID)   // 2048
#define NEG_SLOPE 0.2f
#define H1_HSTRIDE (N_NODES * HID)   // 5,120,000 elements per head slice

typedef unsigned short ushort_t;
typedef unsigned int uint_t;

// ---------------- bf16 helpers ----------------
__device__ inline float b2f(ushort_t u) { return __uint_as_float(((uint_t)u) << 16); }
__device__ inline ushort_t f2b(float f) {
    __hip_bfloat16 h = __float2bfloat16(f);   // RNE
    return *reinterpret_cast<ushort_t*>(&h);
}

__device__ inline void edge_sd(const int* __restrict__ ei, int e, int& s, int& d) {
    if (e < E_REAL) { s = ei[e]; d = ei[E_REAL + e]; }
    else            { s = e - E_REAL; d = s; }   // self-loop
}

// async global->LDS, 16 B per lane; LDS dest = uniform base + lane*16
#define GLDS(g, l) __builtin_amdgcn_global_load_lds( \
    (const __attribute__((address_space(1))) void*)(g), \
    (__attribute__((address_space(3))) void*)(l), 16, 0, 0)

// ---------------- workspace layout (bytes) ----------------
static const long B_H1B  = 0L;           // h1b bf16 (head-major): 40,960,000
static const long B_HB   = 40960000L;    // hb  bf16 (row-major):  40,960,000
static const long B_XB   = 81920000L;    // xb / h2b bf16: 15,360,000
static const long B_W1T  = 97280000L;    // W1^T bf16
static const long B_W2T  = 100425728L;   // W2^T bf16
static const long B_SM   = 103571456L;
// small-buffer offsets (floats/ints, relative to sm)
static const long SM_AS1   = 0;         // 40000
static const long SM_AD1   = 40000;     // 40000
static const long SM_AS2   = 80000;     // 10000
static const long SM_AD2   = 90000;     // 10000
static const long SM_CNT   = 100000;    // 10000 ints (zeroed each call)
static const long SM_ROWS  = 110000;    // 10001 ints
static const long SM_CURS  = 120016;    // 10000 ints
static const long SM_END   = 130016;
static const long B_CSRS = B_SM + SM_END * 4;   // 90000 ints (src)

// ---------------- cast fp32 -> bf16 (row-major, 8/thread) ----------------
__global__ __launch_bounds__(256)
void cast_bf16(const float* __restrict__ in, ushort_t* __restrict__ o, long n) {
    long i = ((long)blockIdx.x * 256 + threadIdx.x) * 8;
    if (i >= n) return;
    float4 v0 = *(const float4*)(in + i);
    float4 v1 = *(const float4*)(in + i + 4);
    ushort_t r[8] = {f2b(v0.x), f2b(v0.y), f2b(v0.z), f2b(v0.w),
                     f2b(v1.x), f2b(v1.y), f2b(v1.z), f2b(v1.w)};
    *(uint4*)(o + i) = *(uint4*)r;
}

// ---------------- cast + transpose: W[K][N] fp32 -> WT[N][K] bf16 ----------
__global__ __launch_bounds__(256)
void cast_transpose(const float* __restrict__ W, ushort_t* __restrict__ WT,
                    int K, int N) {
    __shared__ ushort_t t[32][33];
    const int n0 = blockIdx.x * 32, k0 = blockIdx.y * 32;
    const int tx = threadIdx.x & 31, ty = threadIdx.x >> 5;
#pragma unroll
    for (int i = 0; i < 4; ++i) {
        int k = ty + i * 8;
        t[k][tx] = f2b(W[(long)(k0 + k) * N + n0 + tx]);
    }
    __syncthreads();
#pragma unroll
    for (int i = 0; i < 4; ++i) {
        int n = ty + i * 8;
        WT[(long)(n0 + n) * K + k0 + tx] = t[tx][n];
    }
}

// ---------------- bf16 MFMA GEMM (128x128x32, async LDS staging) ----------
typedef short bf16x8 __attribute__((ext_vector_type(8)));
typedef float f32x4 __attribute__((ext_vector_type(4)));

#define BM 128
#define BN 128
#define BK 32

template<int CMODE>
__global__ __launch_bounds__(256)
void gemm_bf16(const ushort_t* __restrict__ A, const ushort_t* __restrict__ BT,
               ushort_t* __restrict__ C, int M, int N, int K) {
    __shared__ ushort_t As[BM * BK];
    __shared__ ushort_t Bs[BN * BK];
    const int tid  = threadIdx.x;
    const int wave = tid >> 6, lane = tid & 63;
    const int quad = lane >> 4, l16 = lane & 15;
    const int bm = blockIdx.y * BM, bn = blockIdx.x * BN;
    const int wr = (wave >> 1) * 64, wc = (wave & 1) * 64;

    const int ch0 = wave * 128 + lane;
    const int ch1 = ch0 + 64;
    const int r0 = ch0 >> 2, c0 = (ch0 & 3) ^ ((r0 >> 1) & 3);
    const int r1 = ch1 >> 2, c1 = (ch1 & 3) ^ ((r1 >> 1) & 3);
    const ushort_t* a0 = A + (long)(bm + r0) * K + c0 * 8;
    const ushort_t* a1 = A + (long)(bm + r1) * K + c1 * 8;
    const ushort_t* b0 = BT + (long)(bn + r0) * K + c0 * 8;
    const ushort_t* b1 = BT + (long)(bn + r1) * K + c1 * 8;
    ushort_t* lA0 = As + (wave * 128) * 8;        // HW adds lane*16 B
    ushort_t* lA1 = As + (wave * 128 + 64) * 8;
    ushort_t* lB0 = Bs + (wave * 128) * 8;
    ushort_t* lB1 = Bs + (wave * 128 + 64) * 8;

    const int swz = (l16 >> 1) & 3;
    f32x4 acc[4][4] = {};

    for (int k0 = 0; k0 < K; k0 += BK) {
        GLDS(a0 + k0, lA0);
        GLDS(a1 + k0, lA1);
        GLDS(b0 + k0, lB0);
        GLDS(b1 + k0, lB1);
        __syncthreads();
        bf16x8 af[4], bfr[4];
#pragma unroll
        for (int i = 0; i < 4; ++i) {
            af[i]  = *(const bf16x8*)(As + ((wr + i * 16 + l16) * 4 + (quad ^ swz)) * 8);
            bfr[i] = *(const bf16x8*)(Bs + ((wc + i * 16 + l16) * 4 + (quad ^ swz)) * 8);
        }
#pragma unroll
        for (int i = 0; i < 4; ++i)
#pragma unroll
            for (int j = 0; j < 4; ++j)
                acc[i][j] = __builtin_amdgcn_mfma_f32_16x16x32_bf16(
                    af[i], bfr[j], acc[i][j], 0, 0, 0);
        __syncthreads();
    }

#pragma unroll
    for (int i = 0; i < 4; ++i) {
#pragma unroll
        for (int r = 0; r < 4; ++r) {
            int row = bm + wr + i * 16 + quad * 4 + r;
            if (row >= M) continue;
#pragma unroll
            for (int j = 0; j < 4; ++j) {
                int col = bn + wc + j * 16 + l16;
                if (CMODE == 0) {
                    C[(long)row * N + col] = f2b(acc[i][j][r]);
                } else {
                    C[(long)(col >> 9) * H1_HSTRIDE + (long)row * HID + (col & 511)]
                        = f2b(acc[i][j][r]);
                }
            }
        }
    }
}

// ---------------- attention dots, layer 1 (head-major h1) ----------------
__global__ __launch_bounds__(256)
void attn1(const ushort_t* __restrict__ h, const float* __restrict__ a_s,
           const float* __restrict__ a_d, float* __restrict__ os,
           float* __restrict__ od) {
    const int n = blockIdx.x;
    const int w = threadIdx.x >> 6, lane = threadIdx.x & 63;
    uint4 hv = *(const uint4*)(h + (long)w * H1_HSTRIDE + (long)n * HID + lane * 8);
    const float* asp = a_s + w * HID + lane * 8;
    const float* adp = a_d + w * HID + lane * 8;
    const ushort_t* pb = (const ushort_t*)&hv;
    float ps = 0.f, pd = 0.f;
#pragma unroll
    for (int c = 0; c < 8; ++c) {
        float v = b2f(pb[c]);
        ps += v * asp[c];
        pd += v * adp[c];
    }
#pragma unroll
    for (int off = 32; off > 0; off >>= 1) {
        ps += __shfl_down(ps, off);
        pd += __shfl_down(pd, off);
    }
    if (lane == 0) { os[n * HEADS + w] = ps; od[n * HEADS + w] = pd; }
}

// ---------------- attention dots, layer 2 (H=1, D=768) -------------------
__global__ __launch_bounds__(256)
void attn2(const ushort_t* __restrict__ h, const float* __restrict__ a_s,
           const float* __restrict__ a_d, float* __restrict__ os,
           float* __restrict__ od) {
    __shared__ float rs[4], rd[4];
    const int n = blockIdx.x, tid = threadIdx.x;
    const int w = tid >> 6, lane = tid & 63;
    float ps = 0.f, pd = 0.f;
#pragma unroll
    for (int j = 0; j < 3; ++j) {
        int c = tid + j * 256;
        float v = b2f(h[(long)n * OUT_DIM + c]);
        ps += v * a_s[c];
        pd += v * a_d[c];
    }
#pragma unroll
    for (int off = 32; off > 0; off >>= 1) {
        ps += __shfl_down(ps, off);
        pd += __shfl_down(pd, off);
    }
    if (lane == 0) { rs[w] = ps; rd[w] = pd; }
    __syncthreads();
    if (tid == 0) {
        os[n] = rs[0] + rs[1] + rs[2] + rs[3];
        od[n] = rd[0] + rd[1] + rd[2] + rd[3];
    }
}

// ---------------- CSR build ----------------
__global__ __launch_bounds__(256)
void hist_dst(const int* __restrict__ ei, int* __restrict__ cnt) {
    int e = blockIdx.x * 256 + threadIdx.x;
    if (e >= E_TOTAL) return;
    int s, d; edge_sd(ei, e, s, d);
    atomicAdd(&cnt[d], 1);
}

#define SCAN_CH 40
__global__ __launch_bounds__(256)
void scan_nodes(const int* __restrict__ cnt, int* __restrict__ rows,
                int* __restrict__ curs) {
    __shared__ int part[256];
    const int tid = threadIdx.x;
    const int base = tid * SCAN_CH;
    int local[SCAN_CH];
    int sum = 0;
#pragma unroll
    for (int i = 0; i < SCAN_CH; ++i) {
        int idx = base + i;
        int v = (idx < N_NODES) ? cnt[idx] : 0;
        local[i] = v; sum += v;
    }
    part[tid] = sum;
    __syncthreads();
    for (int off = 1; off < 256; off <<= 1) {
        int v = (tid >= off) ? part[tid - off] : 0;
        __syncthreads();
        part[tid] += v;
        __syncthreads();
    }
    int run = part[tid] - sum;   // exclusive prefix
#pragma unroll
    for (int i = 0; i < SCAN_CH; ++i) {
        int idx = base + i;
        if (idx < N_NODES) { rows[idx] = run; curs[idx] = run; run += local[i]; }
    }
    if (tid == 255) rows[N_NODES] = run;
}

__global__ __launch_bounds__(256)
void scatter_edges(const int* __restrict__ ei, int* __restrict__ curs,
                   int* __restrict__ csr_src) {
    int e = blockIdx.x * 256 + threadIdx.x;
    if (e >= E_TOTAL) return;
    int s, d; edge_sd(ei, e, s, d);
    int pos = atomicAdd(&curs[d], 1);
    csr_src[pos] = s;
}

// ---------------- layer-1 aggregate + fused softmax + bias + ELU ---------
// grid (N_NODES, HEADS), 64 threads = 1 wave per (node, head); lane covers
// 8 contiguous channels (full 512-ch head row, 1 KB per edge read).
// softmax folded in: out = (sum_e ex_e h[s_e]) / (sum_e ex_e), ex computed
// inline from as/ad dots (wave-uniform scalar work, ~deg exps per wave).
__global__ __launch_bounds__(64)
void agg1(const int* __restrict__ rows, const int* __restrict__ csr_src,
          const float* __restrict__ as_n, const float* __restrict__ ad_n,
          const ushort_t* __restrict__ hf, const float* __restrict__ b1,
          ushort_t* __restrict__ o) {
    const int n = blockIdx.x, hh = blockIdx.y, lane = threadIdx.x;
    const int beg = rows[n], end = rows[n + 1];
    const ushort_t* hsl = hf + (long)hh * H1_HSTRIDE;
    const float adv = ad_n[(long)n * HEADS + hh];
    float acc[8] = {};
    float dsum = 0.f;
    for (int k = beg; k < end; k += 4) {
        int nk = end - k; if (nk > 4) nk = 4;
        uint4 v[4]; float ex[4];
#pragma unroll
        for (int u = 0; u < 4; ++u) {
            if (u < nk) {
                int s = csr_src[k + u];
                float sc = as_n[(long)s * HEADS + hh] + adv;
                sc = sc > 0.f ? sc : NEG_SLOPE * sc;
                ex[u] = __expf(sc);
                v[u]  = *(const uint4*)(hsl + (long)s * HID + lane * 8);
            }
        }
#pragma unroll
        for (int u = 0; u < 4; ++u) {
            if (u < nk) {
                dsum += ex[u];
                const ushort_t* p = (const ushort_t*)&v[u];
#pragma unroll
                for (int c = 0; c < 8; ++c) acc[c] += ex[u] * b2f(p[c]);
            }
        }
    }
    const float dinv = 1.f / (dsum + 1e-16f);
    const float* bp = b1 + hh * HID + lane * 8;
    ushort_t r[8];
#pragma unroll
    for (int c = 0; c < 8; ++c) {
        float vv = acc[c] * dinv + bp[c];
        r[c] = f2b(vv > 0.f ? vv : expm1f(vv));
    }
    *(uint4*)(o + (long)n * HD1 + hh * HID + lane * 8) = *(uint4*)r;
}

// ---------------- layer-2 aggregate + fused softmax + bias -> fp32 -------
// 64 threads/node; lane covers 8 ch (uint4) + 4 ch (uint2) = 12 ch.
__global__ __launch_bounds__(64)
void agg2(const int* __restrict__ rows, const int* __restrict__ csr_src,
          const float* __restrict__ as_n, const float* __restrict__ ad_n,
          const ushort_t* __restrict__ hf, const float* __restrict__ b2,
          float* __restrict__ out) {
    const int n = blockIdx.x, lane = threadIdx.x;
    const int beg = rows[n], end = rows[n + 1];
    const float adv = ad_n[n];
    float acc[12] = {};
    float dsum = 0.f;
    for (int k = beg; k < end; k += 4) {
        int nk = end - k; if (nk > 4) nk = 4;
        uint4 v4[4]; uint2 v2[4]; float ex[4];
#pragma unroll
        for (int u = 0; u < 4; ++u) {
            if (u < nk) {
                int s = csr_src[k + u];
                float sc = as_n[s] + adv;
                sc = sc > 0.f ? sc : NEG_SLOPE * sc;
                ex[u] = __expf(sc);
                const ushort_t* hp = hf + (long)s * OUT_DIM;
                v4[u] = *(const uint4*)(hp + lane * 8);
                v2[u] = *(const uint2*)(hp + 512 + lane * 4);
            }
        }
#pragma unroll
        for (int u = 0; u < 4; ++u) {
            if (u < nk) {
                dsum += ex[u];
                const ushort_t* p4 = (const ushort_t*)&v4[u];
                const ushort_t* p2 = (const ushort_t*)&v2[u];
#pragma unroll
                for (int c = 0; c < 8; ++c) acc[c] += ex[u] * b2f(p4[c]);
#pragma unroll
                for (int c = 0; c < 4; ++c) acc[8 + c] += ex[u] * b2f(p2[c]);
            }
        }
    }
    const float dinv = 1.f / (dsum + 1e-16f);
    float* op = out + (long)n * OUT_DIM;
#pragma unroll
    for (int c = 0; c < 8; ++c)
        op[lane * 8 + c] = acc[c] * dinv + b2[lane * 8 + c];
#pragma unroll
    for (int c = 0; c < 4; ++c)
        op[512 + lane * 4 + c] = acc[8 + c] * dinv + b2[512 + lane * 4 + c];
}

extern "C" void kernel_launch(void* const* d_in, const int* in_sizes, int n_in,
                              void* d_out, int out_size, void* d_ws, size_t ws_size,
                              hipStream_t stream) {
    const float* x   = (const float*)d_in[0];
    const int*   ei  = (const int*)d_in[1];
    const float* W1  = (const float*)d_in[2];
    const float* a1s = (const float*)d_in[3];
    const float* a1d = (const float*)d_in[4];
    const float* b1  = (const float*)d_in[5];
    const float* W2  = (const float*)d_in[6];
    const float* a2s = (const float*)d_in[7];
    const float* a2d = (const float*)d_in[8];
    const float* b2  = (const float*)d_in[9];
    float* out = (float*)d_out;
    char* base = (char*)d_ws;

    ushort_t* h1b = (ushort_t*)(base + B_H1B);   // head-major [4][10000][512]
    ushort_t* hb  = (ushort_t*)(base + B_HB);    // row-major  [10000][2048]
    ushort_t* xb  = (ushort_t*)(base + B_XB);
    ushort_t* h2b = xb;
    ushort_t* w1t = (ushort_t*)(base + B_W1T);
    ushort_t* w2t = (ushort_t*)(base + B_W2T);
    float*    sm  = (float*)(base + B_SM);

    float* as1  = sm + SM_AS1;
    float* ad1  = sm + SM_AD1;
    float* as2  = sm + SM_AS2;
    float* ad2  = sm + SM_AD2;
    int* cnt    = (int*)(sm + SM_CNT);
    int* rows   = (int*)(sm + SM_ROWS);
    int* curs   = (int*)(sm + SM_CURS);
    int* csr_src = (int*)(base + B_CSRS);

    // zero the degree histogram only
    hipMemsetAsync(cnt, 0, 10000 * sizeof(int), stream);

    // ---------------- casts + CSR build ----------------
    {
        long nx = (long)N_NODES * IN_DIM;
        cast_bf16<<<(int)(nx / 8 / 256 + 1), 256, 0, stream>>>(x, xb, nx);
        cast_transpose<<<dim3(HD1 / 32, IN_DIM / 32), 256, 0, stream>>>(W1, w1t, IN_DIM, HD1);
        cast_transpose<<<dim3(OUT_DIM / 32, HD1 / 32), 256, 0, stream>>>(W2, w2t, HD1, OUT_DIM);
        hist_dst<<<(E_TOTAL + 255) / 256, 256, 0, stream>>>(ei, cnt);
        scan_nodes<<<1, 256, 0, stream>>>(cnt, rows, curs);
        scatter_edges<<<(E_TOTAL + 255) / 256, 256, 0, stream>>>(ei, curs, csr_src);
    }

    // ---------------- layer 1: GATConv(768 -> 512, heads=4, concat) --------
    gemm_bf16<1><<<dim3(HD1 / BN, (N_NODES + BM - 1) / BM), 256, 0, stream>>>(
        xb, w1t, h1b, N_NODES, HD1, IN_DIM);
    attn1<<<N_NODES, 256, 0, stream>>>(h1b, a1s, a1d, as1, ad1);
    agg1<<<dim3(N_NODES, HEADS), 64, 0, stream>>>(
        rows, csr_src, as1, ad1, h1b, b1, hb);

    // ---------------- layer 2: GATConv(2048 -> 768, heads=1, mean) ---------
    gemm_bf16<0><<<dim3(OUT_DIM / BN, (N_NODES + BM - 1) / BM), 256, 0, stream>>>(
        hb, w2t, h2b, N_NODES, OUT_DIM, HD1);
    attn2<<<N_NODES, 256, 0, stream>>>(h2b, a2s, a2d, as2, ad2);
    agg2<<<N_NODES, 64, 0, stream>>>(
        rows, csr_src, as2, ad2, h2b, b2, out);
}